// Round 23
// baseline (180.134 us; speedup 1.0000x reference)
//
#include <hip/hip_runtime.h>
#include <hip/hip_fp16.h>

#define NN 100000
#define NE 800000
#define NZB2 1563              // ceil(NN/64) zpool blocks
#define NRA 25                 // ceil(NZB2/64) stage-A reduce blocks
#define SRCMASK 0x01FFFFFF

typedef short bf16x8 __attribute__((ext_vector_type(8)));
typedef float f32x4 __attribute__((ext_vector_type(4)));

__device__ __forceinline__ float wave_reduce_sum(float v) {
    #pragma unroll
    for (int o = 32; o > 0; o >>= 1) v += __shfl_down(v, o, 64);
    return v; // valid in lane 0
}

__device__ __forceinline__ unsigned short f2bf(float f) {
    unsigned u = __float_as_uint(f);
    unsigned r = (u + 0x7FFFu + ((u >> 16) & 1u)) >> 16;
    return (unsigned short)r;
}
__device__ __forceinline__ float bf2f(unsigned short b) {
    return __uint_as_float(((unsigned)b) << 16);
}
__device__ __forceinline__ float bflo(unsigned u) {   // low bf16 of u32
    return __uint_as_float(u << 16);
}
__device__ __forceinline__ float bfhi(unsigned u) {   // high bf16 of u32
    return __uint_as_float(u & 0xFFFF0000u);
}
__device__ __forceinline__ unsigned pk2(float a, float b) {
    return (unsigned)f2bf(a) | ((unsigned)f2bf(b) << 16);
}
// fp8 e4m3fn via fp16-scale trick
__device__ __forceinline__ unsigned char f2fp8(float f) {
    __half h = __float2half(f * 0.00390625f);   // /256, RTNE
    unsigned short b = __half_as_ushort(h);
    unsigned s = (b >> 8) & 0x80u;
    unsigned mag = b & 0x7FFFu;
    mag = (mag + 0x3Fu + ((mag >> 7) & 1u)) >> 7;  // RTNE to 8-bit em
    if (mag > 0x7Eu) mag = 0x7Eu;                   // clamp (max 448, avoid NaN)
    return (unsigned char)(s | mag);
}
__device__ __forceinline__ float dfp8(unsigned v) {
    unsigned short hb = (unsigned short)(((v & 0x80u) << 8) | ((v & 0x7Fu) << 7));
    return __half2float(__ushort_as_half(hb)) * 256.f;
}

// zero hist: 25000 int4 stores
__global__ void k_zero(int4* __restrict__ hist4) {
    int i = blockIdx.x * 256 + threadIdx.x;
    if (i < NN / 4) hist4[i] = make_int4(0, 0, 0, 0);
}

// cb layout (floats): [0..27] vs1(k*4+h)  [28..55] vd1  [56..59] c1[h]  [60] c2
// W2fr: 5 col-tiles x 8 k-slices, B-fragment order; tile ct=4 col0=W2@as2, col1=W2@ad2
__global__ void k_pre(const float* __restrict__ W1, const float* __restrict__ as1,
                      const float* __restrict__ ad1,
                      const float* __restrict__ We1, const float* __restrict__ ae1,
                      const float* __restrict__ We2, const float* __restrict__ ae2,
                      const float* __restrict__ W2, const float* __restrict__ as2,
                      const float* __restrict__ ad2,
                      float* __restrict__ cb, unsigned short* __restrict__ W2fr) {
    int t = threadIdx.x;
    if (blockIdx.x == 0) {
        if (t < 28) {
            int k = t >> 2, h = t & 3;
            float s = 0.f, d = 0.f;
            for (int c = 0; c < 64; ++c) {
                float w = W1[k * 256 + h * 64 + c];
                s += w * as1[h * 64 + c];
                d += w * ad1[h * 64 + c];
            }
            cb[t] = s; cb[28 + t] = d;
        } else if (t < 32) {
            int h = t - 28;
            float s = 0.f;
            for (int c = 0; c < 64; ++c) s += We1[h * 64 + c] * ae1[h * 64 + c];
            cb[56 + h] = s;
        } else if (t == 32) {
            float s = 0.f;
            for (int c = 0; c < 64; ++c) s += We2[c] * ae2[c];
            cb[60] = s;
        }
    } else {
        int o = (blockIdx.x - 1) * 256 + t;        // 0..20479
        if (o >= 20480) return;
        int i = o & 7, l = (o >> 3) & 63, rest = o >> 9;
        int ct = rest % 5, ks = rest / 5;
        int k = ks * 32 + ((l >> 4) * 8) + i;
        int cl = l & 15;
        if (ct < 4) {
            W2fr[o] = f2bf(W2[k * 64 + ct * 16 + cl]);
        } else if (cl < 2) {
            const float* av = (cl == 0) ? as2 : ad2;
            float s = 0.f;
            for (int j = 0; j < 64; ++j) s += W2[k * 64 + j] * av[j];
            W2fr[o] = f2bf(s);
        } else {
            W2fr[o] = 0;
        }
    }
}

// per-node: interleaved node record nrec[2n]=packed attention, nrec[2n+1]=packed x;
// fused dst histogram capturing per-edge rank
__global__ void k_node1h(const float* __restrict__ x, const float* __restrict__ cb,
                         const int* __restrict__ dst,
                         uint4* __restrict__ nrec, int* __restrict__ hist,
                         int* __restrict__ rank) {
    int n = blockIdx.x * 256 + threadIdx.x;
    if (n >= NN) return;
    float xv[7];
    #pragma unroll
    for (int k = 0; k < 7; ++k) xv[k] = x[n * 7 + k];
    float s[4] = {0.f, 0.f, 0.f, 0.f}, d[4] = {0.f, 0.f, 0.f, 0.f};
    #pragma unroll
    for (int k = 0; k < 7; ++k)
        #pragma unroll
        for (int h = 0; h < 4; ++h) {
            s[h] += xv[k] * cb[k * 4 + h];
            d[h] += xv[k] * cb[28 + k * 4 + h];
        }
    nrec[2 * n] = make_uint4(pk2(s[0], s[1]), pk2(s[2], s[3]),
                             pk2(d[0], d[1]), pk2(d[2], d[3]));
    nrec[2 * n + 1] = make_uint4(pk2(xv[0], xv[1]), pk2(xv[2], xv[3]),
                                 pk2(xv[4], xv[5]), pk2(xv[6], 1.f));
    // histogram + rank: edges [n*8, n*8+8)
    int e0 = n * 8;
    int4 d0 = *(const int4*)(dst + e0);
    int4 d1 = *(const int4*)(dst + e0 + 4);
    int4 r0, r1;
    r0.x = atomicAdd(&hist[d0.x], 1); r0.y = atomicAdd(&hist[d0.y], 1);
    r0.z = atomicAdd(&hist[d0.z], 1); r0.w = atomicAdd(&hist[d0.w], 1);
    r1.x = atomicAdd(&hist[d1.x], 1); r1.y = atomicAdd(&hist[d1.y], 1);
    r1.z = atomicAdd(&hist[d1.z], 1); r1.w = atomicAdd(&hist[d1.w], 1);
    *(int4*)(rank + e0) = r0;
    *(int4*)(rank + e0 + 4) = r1;
}

// --- 3-phase parallel exclusive scan over hist[NN] -> offs[NN+1] ---
__global__ __launch_bounds__(1024) void k_scanA(const int* __restrict__ hist,
                                                int* __restrict__ bsum) {
    __shared__ int ws[16];
    int i = blockIdx.x * 1024 + threadIdx.x;
    int lane = threadIdx.x & 63, wid = threadIdx.x >> 6;
    int v = (i < NN) ? hist[i] : 0;
    #pragma unroll
    for (int o = 32; o; o >>= 1) v += __shfl_down(v, o, 64);
    if (lane == 0) ws[wid] = v;
    __syncthreads();
    if (wid == 0) {
        int u = (lane < 16) ? ws[lane] : 0;
        #pragma unroll
        for (int o = 8; o; o >>= 1) u += __shfl_down(u, o, 64);
        if (lane == 0) bsum[blockIdx.x] = u;
    }
}

__global__ void k_scanB(const int* __restrict__ bsum, int* __restrict__ bexcl) {
    __shared__ int w0tot;
    int t = threadIdx.x, lane = t & 63, wid = t >> 6;
    int v = (t < 98) ? bsum[t] : 0;
    int s = v;
    #pragma unroll
    for (int d = 1; d < 64; d <<= 1) { int u = __shfl_up(s, d, 64); if (lane >= d) s += u; }
    if (t == 63) w0tot = s;
    __syncthreads();
    if (wid == 1) s += w0tot;
    if (t < 98) bexcl[t] = s - v;
}

__global__ __launch_bounds__(1024) void k_scanC(const int* __restrict__ hist,
                                                const int* __restrict__ bexcl,
                                                int* __restrict__ offs) {
    __shared__ int ws[16];
    int b = blockIdx.x;
    int i = b * 1024 + threadIdx.x;
    int lane = threadIdx.x & 63, wid = threadIdx.x >> 6;
    int v = (i < NN) ? hist[i] : 0;
    int s = v;
    #pragma unroll
    for (int d = 1; d < 64; d <<= 1) { int u = __shfl_up(s, d, 64); if (lane >= d) s += u; }
    if (lane == 63) ws[wid] = s;
    __syncthreads();
    if (wid == 0) {
        int u2 = (lane < 16) ? ws[lane] : 0;
        #pragma unroll
        for (int d = 1; d < 16; d <<= 1) { int uu = __shfl_up(u2, d, 64); if (lane >= d) u2 += uu; }
        if (lane < 16) ws[lane] = u2;
    }
    __syncthreads();
    int incl = s + (wid ? ws[wid - 1] : 0) + bexcl[b];
    if (i < NN) offs[i + 1] = incl;
    if (i == 0) offs[0] = 0;
}

// minimal scatter: 8B record {src | (dst&63)<<25, ea}; atomic-free; 2 edges/thread
__global__ void k_scatter(const int* __restrict__ src, const int* __restrict__ dst,
                          const float* __restrict__ ea, const int* __restrict__ rank,
                          const int* __restrict__ offs, int2* __restrict__ es2) {
    int e0 = (blockIdx.x * 256 + threadIdx.x) * 2;
    if (e0 >= NE) return;
    int2 s2 = *(const int2*)(src + e0);
    int2 d2 = *(const int2*)(dst + e0);
    float2 a2 = *(const float2*)(ea + e0);
    int2 r2 = *(const int2*)(rank + e0);
    int p0 = offs[d2.x] + r2.x;
    int p1 = offs[d2.y] + r2.y;
    es2[p0] = make_int2(s2.x | ((d2.x & 63) << 25), __float_as_int(a2.x));
    es2[p1] = make_int2(s2.y | ((d2.y & 63) << 25), __float_as_int(a2.y));
}

// fused conv1: stage computes conv1 edge weights inline (anode gather, same line as xpack)
// -> packed-LDS two-phase segmented reduce -> h -> MFMA (5th col-tile = a_src2/a_dst2)
__global__ __launch_bounds__(256, 7) void k_conv1red(
    const uint4* __restrict__ nrec, const float* __restrict__ W1, const float* __restrict__ b1,
    const float* __restrict__ cb, const int* __restrict__ offs,
    const int2* __restrict__ es2, const unsigned short* __restrict__ W2fr,
    unsigned char* __restrict__ xh2f, float* __restrict__ a_src2, float* __restrict__ a_dst2) {
    // overlay: xs/wsx (phases 1-2) share storage with hs (finish/MFMA phases)
    __shared__ __attribute__((aligned(16))) unsigned char smem[16896];
    uint4* xs = (uint4*)smem;                                   // [256] 4096 B
    uint2* wsx = (uint2*)(smem + 4096);                         // [256] 2048 B
    typedef unsigned short hsrow[264];
    hsrow* hs = (hsrow*)smem;                                   // [32][264] 16896 B
    __shared__ int soffs[33];
    __shared__ uint2 ad1L[32];
    __shared__ float ms[32][33];
    int t = threadIdx.x, lane = t & 63, wid = t >> 6;
    int n0 = blockIdx.x * 32;
    if (t <= 32) soffs[t] = offs[n0 + t];
    if (t < 32) {
        uint4 a = nrec[2 * (n0 + t)];
        ad1L[t] = make_uint2(a.z, a.w);
    }
    float w1r[7][4], b1r[4];
    #pragma unroll
    for (int k = 0; k < 7; ++k)
        #pragma unroll
        for (int h = 0; h < 4; ++h) w1r[k][h] = W1[k * 256 + h * 64 + lane];
    #pragma unroll
    for (int h = 0; h < 4; ++h) b1r[h] = b1[h * 64 + lane];
    float c56 = cb[56], c57 = cb[57], c58 = cb[58], c59 = cb[59];
    __syncthreads();
    int E0 = soffs[0], E1 = soffs[32];
    int g = t >> 3, q = t & 7;
    int go0 = soffs[g], go1 = soffs[g + 1];
    int qh = q >> 1;
    int xsl = (q & 1) ? 0 : 16;    // shift to put selected bf16 in high half
    float mh0 = 0.f, mh1 = 0.f, mh2 = 0.f, mh3 = 0.f;
    for (int C0 = E0; C0 < E1; C0 += 256) {
        int C1 = min(C0 + 256, E1);
        int j = C0 + t;
        if (j < C1) {
            int2 e2 = es2[j];
            int sx = e2.x & SRCMASK;
            int dl = (e2.x >> 25) & 31;
            float eav = __int_as_float(e2.y);
            uint4 ar = nrec[2 * sx];
            xs[t] = nrec[2 * sx + 1];
            uint2 br = ad1L[dl];
            float lg0 = bflo(ar.x) + bflo(br.x) + eav * c56;
            float lg1 = bfhi(ar.x) + bfhi(br.x) + eav * c57;
            float lg2 = bflo(ar.y) + bflo(br.y) + eav * c58;
            float lg3 = bfhi(ar.y) + bfhi(br.y) + eav * c59;
            lg0 = lg0 >= 0.f ? lg0 : 0.2f * lg0;
            lg1 = lg1 >= 0.f ? lg1 : 0.2f * lg1;
            lg2 = lg2 >= 0.f ? lg2 : 0.2f * lg2;
            lg3 = lg3 >= 0.f ? lg3 : 0.2f * lg3;
            wsx[t] = make_uint2(pk2(__expf(lg0), __expf(lg1)),
                                pk2(__expf(lg2), __expf(lg3)));
        }
        __syncthreads();
        int lo = max(go0, C0) - C0, hi = min(go1, C1) - C0;
        for (int jj = lo; jj < hi; ++jj) {
            unsigned xu = ((const unsigned*)&xs[jj])[qh];
            float xv = __uint_as_float((xu << xsl) & 0xFFFF0000u);
            uint2 wv = wsx[jj];
            mh0 = fmaf(bflo(wv.x), xv, mh0);
            mh1 = fmaf(bfhi(wv.x), xv, mh1);
            mh2 = fmaf(bflo(wv.y), xv, mh2);
            mh3 = fmaf(bfhi(wv.y), xv, mh3);
        }
        __syncthreads();
    }
    ms[g][0 * 8 + q] = mh0; ms[g][1 * 8 + q] = mh1;
    ms[g][2 * 8 + q] = mh2; ms[g][3 * 8 + q] = mh3;
    __syncthreads();          // xs/wsx dead from here; hs may now overwrite
    // finish: 8 nodes per wave, lane = channel
    for (int gi = wid * 8; gi < wid * 8 + 8; ++gi) {
        bool has = soffs[gi + 1] > soffs[gi];
        #pragma unroll
        for (int h = 0; h < 4; ++h) {
            float rz = __builtin_amdgcn_rcpf(ms[gi][h * 8 + 7]);
            float a = 0.f;
            #pragma unroll
            for (int k = 0; k < 7; ++k) a = fmaf(ms[gi][h * 8 + k], w1r[k][h], a);
            float mm = (has ? a * rz : 0.f) + b1r[h];
            float hv = mm > 0.f ? mm : (__expf(mm) - 1.f);
            hs[gi][h * 64 + lane] = f2bf(hv);
        }
    }
    __syncthreads();
    // MFMA: 2 node-tiles x 5 col-tiles (ct=4 -> a_src2/a_dst2 columns)
    int row = lane & 15, kg = lane >> 4;
    #pragma unroll
    for (int u = wid; u < 10; u += 4) {
        int nt = u & 1, ct = u >> 1;
        f32x4 acc = {0.f, 0.f, 0.f, 0.f};
        #pragma unroll
        for (int ks = 0; ks < 8; ++ks) {
            bf16x8 av = *(const bf16x8*)&hs[nt * 16 + row][ks * 32 + kg * 8];
            bf16x8 bv = *(const bf16x8*)(W2fr + (((ks * 5 + ct) * 64) + lane) * 8);
            acc = __builtin_amdgcn_mfma_f32_16x16x32_bf16(av, bv, acc, 0, 0, 0);
        }
        if (ct < 4) {
            #pragma unroll
            for (int i = 0; i < 4; ++i)
                xh2f[(n0 + nt * 16 + kg * 4 + i) * 64 + ct * 16 + row] = f2fp8(acc[i]);
        } else if (row == 0) {
            #pragma unroll
            for (int i = 0; i < 4; ++i) a_src2[n0 + nt * 16 + kg * 4 + i] = acc[i];
        } else if (row == 1) {
            #pragma unroll
            for (int i = 0; i < 4; ++i) a_dst2[n0 + nt * 16 + kg * 4 + i] = acc[i];
        }
    }
}

// conv2 normalization + fused cluster pooling; 64-node blocks, 512 threads,
// balanced edge-parallel pass 2 (64 slots x 8 lanes)
__global__ __launch_bounds__(512) void k_zpool(
    const int2* __restrict__ es2, const int* __restrict__ offs,
    const float* __restrict__ a_src2, const float* __restrict__ a_dst2,
    const int* __restrict__ assign, const float* __restrict__ cb,
    const unsigned char* __restrict__ xh2f, const float* __restrict__ x,
    float* __restrict__ partial) {
    __shared__ int soffs[65];
    __shared__ float adL[64];
    __shared__ int asgL[64];
    __shared__ float ewL[1024];
    __shared__ int sL[1024];
    __shared__ float rzL[64];
    __shared__ float zacc[64];
    __shared__ float csum[264];
    int t = threadIdx.x;
    int n0 = blockIdx.x * 64;
    if (t <= 64) soffs[t] = offs[min(n0 + t, NN)];
    if (t < 64) {
        int nn = min(n0 + t, NN - 1);
        adL[t] = a_dst2[nn];
        asgL[t] = assign[nn];
        zacc[t] = 0.f;
    }
    for (int i = t; i < 264; i += 512) csum[i] = 0.f;
    __syncthreads();
    int E0 = soffs[0], E1 = soffs[64];
    int span = E1 - E0;
    float c2 = cb[60];
    #pragma unroll
    for (int c0 = 0; c0 < 1024; c0 += 512) {
        int j = c0 + t;
        if (j < span && j < 1024) {
            int2 e2 = es2[E0 + j];
            int sx = e2.x & SRCMASK;
            int d6 = (e2.x >> 25) & 63;
            float lg = a_src2[sx] + adL[d6] + __int_as_float(e2.y) * c2;
            lg = lg >= 0.f ? lg : 0.2f * lg;
            ewL[j] = __expf(lg);
            sL[j] = e2.x;
        }
    }
    // rare overflow edges: accumulate z via LDS atomics
    for (int j = 1024 + t; j < span; j += 512) {
        int2 e2 = es2[E0 + j];
        int d6 = (e2.x >> 25) & 63;
        float lg = a_src2[e2.x & SRCMASK] + adL[d6] + __int_as_float(e2.y) * c2;
        lg = lg >= 0.f ? lg : 0.2f * lg;
        atomicAdd(&zacc[d6], __expf(lg));
    }
    __syncthreads();
    // per-node z from ewL (8 lanes per node, 64 nodes)
    int gz = t >> 3, q8 = t & 7;
    {
        int lo = soffs[gz] - E0, hi = soffs[gz + 1] - E0;
        int hicap = min(hi, 1024);
        float z = 0.f;
        for (int jj = lo + q8; jj < hicap; jj += 8) z += ewL[jj];
        z += __shfl_xor(z, 1, 64);
        z += __shfl_xor(z, 2, 64);
        z += __shfl_xor(z, 4, 64);
        if (q8 == 0) rzL[gz] = __builtin_amdgcn_rcpf(z + zacc[gz]);
    }
    __syncthreads();
    // pass 2: edge-parallel slots (64 slots x 8 lanes), 4-cluster predicated regs
    int slot = t >> 3, q = t & 7;
    const unsigned char* pbase = xh2f + q * 8;
    float ac[4][8];
    #pragma unroll
    for (int c = 0; c < 4; ++c)
        #pragma unroll
        for (int k = 0; k < 8; ++k) ac[c][k] = 0.f;
    #pragma unroll 2
    for (int jj = slot; jj < span; jj += 64) {
        int zv; float ew;
        if (jj < 1024) {
            zv = sL[jj];
            ew = ewL[jj];
        } else {
            int2 e2 = es2[E0 + jj];
            zv = e2.x;
            int d6o = (zv >> 25) & 63;
            float lg = a_src2[zv & SRCMASK] + adL[d6o] + __int_as_float(e2.y) * c2;
            lg = lg >= 0.f ? lg : 0.2f * lg;
            ew = __expf(lg);
        }
        int sx = zv & SRCMASK;
        int d6 = (zv >> 25) & 63;
        float wv = ew * rzL[d6];
        int cc = asgL[d6];
        uint2 u = *(const uint2*)(pbase + sx * 64);
        float v0 = dfp8(u.x & 255u), v1 = dfp8((u.x >> 8) & 255u);
        float v2 = dfp8((u.x >> 16) & 255u), v3 = dfp8(u.x >> 24);
        float v4 = dfp8(u.y & 255u), v5 = dfp8((u.y >> 8) & 255u);
        float v6 = dfp8((u.y >> 16) & 255u), v7 = dfp8(u.y >> 24);
        #pragma unroll
        for (int c = 0; c < 4; ++c) {
            float wc = (cc == c) ? wv : 0.f;
            ac[c][0] = fmaf(wc, v0, ac[c][0]);
            ac[c][1] = fmaf(wc, v1, ac[c][1]);
            ac[c][2] = fmaf(wc, v2, ac[c][2]);
            ac[c][3] = fmaf(wc, v3, ac[c][3]);
            ac[c][4] = fmaf(wc, v4, ac[c][4]);
            ac[c][5] = fmaf(wc, v5, ac[c][5]);
            ac[c][6] = fmaf(wc, v6, ac[c][6]);
            ac[c][7] = fmaf(wc, v7, ac[c][7]);
        }
    }
    // fold 8 slots per wave (lane bits 3,4,5), then 8 lanes/wave do LDS atomics
    #pragma unroll
    for (int c = 0; c < 4; ++c)
        #pragma unroll
        for (int k = 0; k < 8; ++k) {
            float v = ac[c][k];
            v += __shfl_xor(v, 8, 64);
            v += __shfl_xor(v, 16, 64);
            v += __shfl_xor(v, 32, 64);
            ac[c][k] = v;
        }
    if (((t >> 3) & 7) == 0) {
        #pragma unroll
        for (int c = 0; c < 4; ++c)
            #pragma unroll
            for (int k = 0; k < 8; ++k)
                atomicAdd(&csum[c * 64 + q * 8 + k], ac[c][k]);
    }
    if (t < 64 && n0 + t < NN) {
        int c = asgL[t];
        atomicAdd(&csum[256 + c], 1.f);
        atomicAdd(&csum[260 + c], x[(n0 + t) * 7 + 6]);
    }
    __syncthreads();
    for (int i = t; i < 264; i += 512) partial[blockIdx.x * 264 + i] = csum[i];
}

// stage A: coalesced chunk reduce of partial[NZB2][264] -> part2[NRA][264]
__global__ __launch_bounds__(256) void k_redA(const float* __restrict__ partial,
                                              float* __restrict__ part2) {
    int gblk = blockIdx.x;
    int b0 = gblk * 64, b1 = min(b0 + 64, NZB2);
    int t = threadIdx.x;
    for (int i = t; i < 264; i += 256) {
        float s = 0.f;
        for (int b = b0; b < b1; ++b) s += partial[b * 264 + i];
        part2[gblk * 264 + i] = s;
    }
}

// final head (256 threads): fold part2 -> cluster means (+cnt*b2), actor + critic
__global__ __launch_bounds__(256) void k_head(
    const float* __restrict__ part2, const float* __restrict__ b2,
    const float* __restrict__ A1, const float* __restrict__ ba1,
    const float* __restrict__ A2, const float* __restrict__ ba2,
    const float* __restrict__ C1, const float* __restrict__ bc1,
    const float* __restrict__ C2, const float* __restrict__ bc2,
    float* __restrict__ out) {
    __shared__ float gaccL[264];
    __shared__ float zc[4][64];
    __shared__ float cfs[4];
    __shared__ float logits[4];
    __shared__ float vpart[4][64];
    int t = threadIdx.x;
    for (int i = t; i < 264; i += 256) {
        float s = 0.f;
        for (int g = 0; g < NRA; ++g) s += part2[g * 264 + i];
        gaccL[i] = s;
    }
    __syncthreads();
    int j = t & 63, wv = t >> 6;   // wave wv handles cluster wv
    float cnt = gaccL[256 + wv];
    float den = fmaxf(cnt, 1.f);
    zc[wv][j] = (cnt > 0.f) ? (gaccL[wv * 64 + j] + cnt * b2[j]) / den : 0.f;
    if (t < 4) {
        float cc = gaccL[256 + t];
        cfs[t] = (cc > 0.f) ? gaccL[260 + t] / fmaxf(cc, 1.f) : 0.f;
    }
    __syncthreads();
    // actor: cluster wv
    float tv = ba1[j];
    for (int k = 0; k < 64; ++k) tv = fmaf(zc[wv][k], A1[k * 64 + j], tv);
    tv = fmaf(cfs[wv], A1[64 * 64 + j], tv);
    tv = fmaxf(tv, 0.f);
    float sred = wave_reduce_sum(tv * A2[j]);
    if (j == 0) logits[wv] = sred + ba2[0];
    // critic partials: wave wv covers k in [wv*64, (wv+1)*64)
    float vj = (wv == 0) ? bc1[j] : 0.f;
    for (int kk = 0; kk < 64; ++kk) vj = fmaf(zc[wv][kk], C1[(wv * 64 + kk) * 64 + j], vj);
    vpart[wv][j] = vj;
    __syncthreads();
    if (wv == 0) {
        float vv = fmaxf(vpart[0][j] + vpart[1][j] + vpart[2][j] + vpart[3][j], 0.f);
        float v = wave_reduce_sum(vv * C2[j]);
        if (j == 0) {
            float m = fmaxf(fmaxf(logits[0], logits[1]), fmaxf(logits[2], logits[3]));
            float e0 = __expf(logits[0] - m), e1 = __expf(logits[1] - m);
            float e2 = __expf(logits[2] - m), e3 = __expf(logits[3] - m);
            float sum = e0 + e1 + e2 + e3;
            out[0] = e0 / sum; out[1] = e1 / sum; out[2] = e2 / sum; out[3] = e3 / sum;
            out[4] = v + bc2[0];
        }
    }
    out[5 + wv * 64 + j] = zc[wv][j];
}

extern "C" void kernel_launch(void* const* d_in, const int* in_sizes, int n_in,
                              void* d_out, int out_size, void* d_ws, size_t ws_size,
                              hipStream_t stream) {
    const float* x    = (const float*)d_in[0];
    const int*   ei   = (const int*)d_in[1];
    const float* ea   = (const float*)d_in[2];
    const int*   asg  = (const int*)d_in[3];
    const float* W1   = (const float*)d_in[4];
    const float* as1  = (const float*)d_in[5];
    const float* ad1  = (const float*)d_in[6];
    const float* We1  = (const float*)d_in[7];
    const float* ae1  = (const float*)d_in[8];
    const float* b1   = (const float*)d_in[9];
    const float* W2   = (const float*)d_in[10];
    const float* as2  = (const float*)d_in[11];
    const float* ad2  = (const float*)d_in[12];
    const float* We2  = (const float*)d_in[13];
    const float* ae2  = (const float*)d_in[14];
    const float* b2   = (const float*)d_in[15];
    const float* A1   = (const float*)d_in[16];
    const float* ba1  = (const float*)d_in[17];
    const float* A2   = (const float*)d_in[18];
    const float* ba2  = (const float*)d_in[19];
    const float* C1   = (const float*)d_in[20];
    const float* bc1  = (const float*)d_in[21];
    const float* C2   = (const float*)d_in[22];
    const float* bc2  = (const float*)d_in[23];
    const int* src = ei;
    const int* dst = ei + NE;

    char* w = (char*)d_ws;
    size_t off = 0;
    auto alloc = [&](size_t bytes) -> void* {
        void* p = w + off;
        off += (bytes + 255) & ~(size_t)255;
        return p;
    };
    int*   hist   = (int*)alloc(NN * sizeof(int));
    float* partial= (float*)alloc((size_t)NZB2 * 264 * sizeof(float));
    float* part2  = (float*)alloc((size_t)NRA * 264 * sizeof(float));
    uint4* nrec   = (uint4*)alloc((size_t)NN * 2 * sizeof(uint4));
    float* a_src2 = (float*)alloc(NN * sizeof(float));
    float* a_dst2 = (float*)alloc(NN * sizeof(float));
    int*   offs   = (int*)alloc((NN + 1) * sizeof(int));
    int*   rank   = (int*)alloc(NE * sizeof(int));
    int*   bsum   = (int*)alloc(128 * sizeof(int));
    int*   bexcl  = (int*)alloc(128 * sizeof(int));
    int2*  es2    = (int2*)alloc(NE * sizeof(int2));
    unsigned char* xh2f = (unsigned char*)alloc((size_t)NN * 64 * sizeof(unsigned char));
    unsigned short* W2fr = (unsigned short*)alloc(20480 * sizeof(unsigned short));
    float* cb     = (float*)alloc(64 * sizeof(float));
    (void)ws_size; (void)n_in; (void)in_sizes; (void)out_size;

    k_zero<<<98, 256, 0, stream>>>((int4*)hist);
    k_pre<<<81, 256, 0, stream>>>(W1, as1, ad1, We1, ae1, We2, ae2, W2, as2, ad2, cb, W2fr);
    k_node1h<<<(NN + 255) / 256, 256, 0, stream>>>(x, cb, dst, nrec, hist, rank);
    k_scanA<<<98, 1024, 0, stream>>>(hist, bsum);
    k_scanB<<<1, 128, 0, stream>>>(bsum, bexcl);
    k_scanC<<<98, 1024, 0, stream>>>(hist, bexcl, offs);
    k_scatter<<<(NE / 2 + 255) / 256, 256, 0, stream>>>(src, dst, ea, rank, offs, es2);
    k_conv1red<<<NN / 32, 256, 0, stream>>>(nrec, W1, b1, cb, offs, es2,
                                            W2fr, xh2f, a_src2, a_dst2);
    k_zpool<<<NZB2, 512, 0, stream>>>(es2, offs, a_src2, a_dst2, asg, cb, xh2f, x, partial);
    k_redA<<<NRA, 256, 0, stream>>>(partial, part2);
    k_head<<<1, 256, 0, stream>>>(part2, b2, A1, ba1, A2, ba2, C1, bc1, C2, bc2, (float*)d_out);
}

// Round 24
// 166.946 us; speedup vs baseline: 1.0790x; 1.0790x over previous
//
#include <hip/hip_runtime.h>
#include <hip/hip_fp16.h>

#define NN 100000
#define NE 800000
#define NZB2 1563              // ceil(NN/64) zpool blocks
#define NRA 25                 // ceil(NZB2/64) stage-A reduce blocks
#define SRCMASK 0x01FFFFFF

typedef short bf16x8 __attribute__((ext_vector_type(8)));
typedef float f32x4 __attribute__((ext_vector_type(4)));

__device__ __forceinline__ float wave_reduce_sum(float v) {
    #pragma unroll
    for (int o = 32; o > 0; o >>= 1) v += __shfl_down(v, o, 64);
    return v; // valid in lane 0
}

__device__ __forceinline__ unsigned short f2bf(float f) {
    unsigned u = __float_as_uint(f);
    unsigned r = (u + 0x7FFFu + ((u >> 16) & 1u)) >> 16;
    return (unsigned short)r;
}
__device__ __forceinline__ float bf2f(unsigned short b) {
    return __uint_as_float(((unsigned)b) << 16);
}
__device__ __forceinline__ float bflo(unsigned u) {   // low bf16 of u32
    return __uint_as_float(u << 16);
}
__device__ __forceinline__ float bfhi(unsigned u) {   // high bf16 of u32
    return __uint_as_float(u & 0xFFFF0000u);
}
__device__ __forceinline__ unsigned pk2(float a, float b) {
    return (unsigned)f2bf(a) | ((unsigned)f2bf(b) << 16);
}
// fp8 e4m3fn via fp16-scale trick
__device__ __forceinline__ unsigned char f2fp8(float f) {
    __half h = __float2half(f * 0.00390625f);   // /256, RTNE
    unsigned short b = __half_as_ushort(h);
    unsigned s = (b >> 8) & 0x80u;
    unsigned mag = b & 0x7FFFu;
    mag = (mag + 0x3Fu + ((mag >> 7) & 1u)) >> 7;  // RTNE to 8-bit em
    if (mag > 0x7Eu) mag = 0x7Eu;                   // clamp (max 448, avoid NaN)
    return (unsigned char)(s | mag);
}
__device__ __forceinline__ float dfp8(unsigned v) {
    unsigned short hb = (unsigned short)(((v & 0x80u) << 8) | ((v & 0x7Fu) << 7));
    return __half2float(__ushort_as_half(hb)) * 256.f;
}

// zero hist: 25000 int4 stores
__global__ void k_zero(int4* __restrict__ hist4) {
    int i = blockIdx.x * 256 + threadIdx.x;
    if (i < NN / 4) hist4[i] = make_int4(0, 0, 0, 0);
}

// cb layout (floats): [0..27] vs1(k*4+h)  [28..55] vd1  [56..59] c1[h]  [60] c2
// W2fr: 5 col-tiles x 8 k-slices, B-fragment order; tile ct=4 col0=W2@as2, col1=W2@ad2
__global__ void k_pre(const float* __restrict__ W1, const float* __restrict__ as1,
                      const float* __restrict__ ad1,
                      const float* __restrict__ We1, const float* __restrict__ ae1,
                      const float* __restrict__ We2, const float* __restrict__ ae2,
                      const float* __restrict__ W2, const float* __restrict__ as2,
                      const float* __restrict__ ad2,
                      float* __restrict__ cb, unsigned short* __restrict__ W2fr) {
    int t = threadIdx.x;
    if (blockIdx.x == 0) {
        if (t < 28) {
            int k = t >> 2, h = t & 3;
            float s = 0.f, d = 0.f;
            for (int c = 0; c < 64; ++c) {
                float w = W1[k * 256 + h * 64 + c];
                s += w * as1[h * 64 + c];
                d += w * ad1[h * 64 + c];
            }
            cb[t] = s; cb[28 + t] = d;
        } else if (t < 32) {
            int h = t - 28;
            float s = 0.f;
            for (int c = 0; c < 64; ++c) s += We1[h * 64 + c] * ae1[h * 64 + c];
            cb[56 + h] = s;
        } else if (t == 32) {
            float s = 0.f;
            for (int c = 0; c < 64; ++c) s += We2[c] * ae2[c];
            cb[60] = s;
        }
    } else {
        int o = (blockIdx.x - 1) * 256 + t;        // 0..20479
        if (o >= 20480) return;
        int i = o & 7, l = (o >> 3) & 63, rest = o >> 9;
        int ct = rest % 5, ks = rest / 5;
        int k = ks * 32 + ((l >> 4) * 8) + i;
        int cl = l & 15;
        if (ct < 4) {
            W2fr[o] = f2bf(W2[k * 64 + ct * 16 + cl]);
        } else if (cl < 2) {
            const float* av = (cl == 0) ? as2 : ad2;
            float s = 0.f;
            for (int j = 0; j < 64; ++j) s += W2[k * 64 + j] * av[j];
            W2fr[o] = f2bf(s);
        } else {
            W2fr[o] = 0;
        }
    }
}

// per-node: interleaved node record nrec[2n]=packed attention, nrec[2n+1]=packed x;
// fused dst histogram capturing per-edge rank
__global__ void k_node1h(const float* __restrict__ x, const float* __restrict__ cb,
                         const int* __restrict__ dst,
                         uint4* __restrict__ nrec, int* __restrict__ hist,
                         int* __restrict__ rank) {
    int n = blockIdx.x * 256 + threadIdx.x;
    if (n >= NN) return;
    float xv[7];
    #pragma unroll
    for (int k = 0; k < 7; ++k) xv[k] = x[n * 7 + k];
    float s[4] = {0.f, 0.f, 0.f, 0.f}, d[4] = {0.f, 0.f, 0.f, 0.f};
    #pragma unroll
    for (int k = 0; k < 7; ++k)
        #pragma unroll
        for (int h = 0; h < 4; ++h) {
            s[h] += xv[k] * cb[k * 4 + h];
            d[h] += xv[k] * cb[28 + k * 4 + h];
        }
    nrec[2 * n] = make_uint4(pk2(s[0], s[1]), pk2(s[2], s[3]),
                             pk2(d[0], d[1]), pk2(d[2], d[3]));
    nrec[2 * n + 1] = make_uint4(pk2(xv[0], xv[1]), pk2(xv[2], xv[3]),
                                 pk2(xv[4], xv[5]), pk2(xv[6], 1.f));
    // histogram + rank: edges [n*8, n*8+8)
    int e0 = n * 8;
    int4 d0 = *(const int4*)(dst + e0);
    int4 d1 = *(const int4*)(dst + e0 + 4);
    int4 r0, r1;
    r0.x = atomicAdd(&hist[d0.x], 1); r0.y = atomicAdd(&hist[d0.y], 1);
    r0.z = atomicAdd(&hist[d0.z], 1); r0.w = atomicAdd(&hist[d0.w], 1);
    r1.x = atomicAdd(&hist[d1.x], 1); r1.y = atomicAdd(&hist[d1.y], 1);
    r1.z = atomicAdd(&hist[d1.z], 1); r1.w = atomicAdd(&hist[d1.w], 1);
    *(int4*)(rank + e0) = r0;
    *(int4*)(rank + e0 + 4) = r1;
}

// --- 3-phase parallel exclusive scan over hist[NN] -> offs[NN+1] ---
__global__ __launch_bounds__(1024) void k_scanA(const int* __restrict__ hist,
                                                int* __restrict__ bsum) {
    __shared__ int ws[16];
    int i = blockIdx.x * 1024 + threadIdx.x;
    int lane = threadIdx.x & 63, wid = threadIdx.x >> 6;
    int v = (i < NN) ? hist[i] : 0;
    #pragma unroll
    for (int o = 32; o; o >>= 1) v += __shfl_down(v, o, 64);
    if (lane == 0) ws[wid] = v;
    __syncthreads();
    if (wid == 0) {
        int u = (lane < 16) ? ws[lane] : 0;
        #pragma unroll
        for (int o = 8; o; o >>= 1) u += __shfl_down(u, o, 64);
        if (lane == 0) bsum[blockIdx.x] = u;
    }
}

__global__ void k_scanB(const int* __restrict__ bsum, int* __restrict__ bexcl) {
    __shared__ int w0tot;
    int t = threadIdx.x, lane = t & 63, wid = t >> 6;
    int v = (t < 98) ? bsum[t] : 0;
    int s = v;
    #pragma unroll
    for (int d = 1; d < 64; d <<= 1) { int u = __shfl_up(s, d, 64); if (lane >= d) s += u; }
    if (t == 63) w0tot = s;
    __syncthreads();
    if (wid == 1) s += w0tot;
    if (t < 98) bexcl[t] = s - v;
}

__global__ __launch_bounds__(1024) void k_scanC(const int* __restrict__ hist,
                                                const int* __restrict__ bexcl,
                                                int* __restrict__ offs) {
    __shared__ int ws[16];
    int b = blockIdx.x;
    int i = b * 1024 + threadIdx.x;
    int lane = threadIdx.x & 63, wid = threadIdx.x >> 6;
    int v = (i < NN) ? hist[i] : 0;
    int s = v;
    #pragma unroll
    for (int d = 1; d < 64; d <<= 1) { int u = __shfl_up(s, d, 64); if (lane >= d) s += u; }
    if (lane == 63) ws[wid] = s;
    __syncthreads();
    if (wid == 0) {
        int u2 = (lane < 16) ? ws[lane] : 0;
        #pragma unroll
        for (int d = 1; d < 16; d <<= 1) { int uu = __shfl_up(u2, d, 64); if (lane >= d) u2 += uu; }
        if (lane < 16) ws[lane] = u2;
    }
    __syncthreads();
    int incl = s + (wid ? ws[wid - 1] : 0) + bexcl[b];
    if (i < NN) offs[i + 1] = incl;
    if (i == 0) offs[0] = 0;
}

// minimal scatter: 8B record {src | (dst&63)<<25, ea}; atomic-free; 2 edges/thread
__global__ void k_scatter(const int* __restrict__ src, const int* __restrict__ dst,
                          const float* __restrict__ ea, const int* __restrict__ rank,
                          const int* __restrict__ offs, int2* __restrict__ es2) {
    int e0 = (blockIdx.x * 256 + threadIdx.x) * 2;
    if (e0 >= NE) return;
    int2 s2 = *(const int2*)(src + e0);
    int2 d2 = *(const int2*)(dst + e0);
    float2 a2 = *(const float2*)(ea + e0);
    int2 r2 = *(const int2*)(rank + e0);
    int p0 = offs[d2.x] + r2.x;
    int p1 = offs[d2.y] + r2.y;
    es2[p0] = make_int2(s2.x | ((d2.x & 63) << 25), __float_as_int(a2.x));
    es2[p1] = make_int2(s2.y | ((d2.y & 63) << 25), __float_as_int(a2.y));
}

// fused conv1: stage computes conv1 edge weights inline (anode gather, same line as xpack)
// -> packed-LDS two-phase segmented reduce -> h -> MFMA (5th col-tile = a_src2/a_dst2)
__global__ __launch_bounds__(256, 7) void k_conv1red(
    const uint4* __restrict__ nrec, const float* __restrict__ W1, const float* __restrict__ b1,
    const float* __restrict__ cb, const int* __restrict__ offs,
    const int2* __restrict__ es2, const unsigned short* __restrict__ W2fr,
    unsigned char* __restrict__ xh2f, float* __restrict__ a_src2, float* __restrict__ a_dst2) {
    // overlay: xs/wsx (phases 1-2) share storage with hs (finish/MFMA phases)
    __shared__ __attribute__((aligned(16))) unsigned char smem[16896];
    uint4* xs = (uint4*)smem;                                   // [256] 4096 B
    uint2* wsx = (uint2*)(smem + 4096);                         // [256] 2048 B
    typedef unsigned short hsrow[264];
    hsrow* hs = (hsrow*)smem;                                   // [32][264] 16896 B
    __shared__ int soffs[33];
    __shared__ uint2 ad1L[32];
    __shared__ float ms[32][33];
    int t = threadIdx.x, lane = t & 63, wid = t >> 6;
    int n0 = blockIdx.x * 32;
    if (t <= 32) soffs[t] = offs[n0 + t];
    if (t < 32) {
        uint4 a = nrec[2 * (n0 + t)];
        ad1L[t] = make_uint2(a.z, a.w);
    }
    float w1r[7][4], b1r[4];
    #pragma unroll
    for (int k = 0; k < 7; ++k)
        #pragma unroll
        for (int h = 0; h < 4; ++h) w1r[k][h] = W1[k * 256 + h * 64 + lane];
    #pragma unroll
    for (int h = 0; h < 4; ++h) b1r[h] = b1[h * 64 + lane];
    float c56 = cb[56], c57 = cb[57], c58 = cb[58], c59 = cb[59];
    __syncthreads();
    int E0 = soffs[0], E1 = soffs[32];
    int g = t >> 3, q = t & 7;
    int go0 = soffs[g], go1 = soffs[g + 1];
    int qh = q >> 1;
    int xsl = (q & 1) ? 0 : 16;    // shift to put selected bf16 in high half
    float mh0 = 0.f, mh1 = 0.f, mh2 = 0.f, mh3 = 0.f;
    for (int C0 = E0; C0 < E1; C0 += 256) {
        int C1 = min(C0 + 256, E1);
        int j = C0 + t;
        if (j < C1) {
            int2 e2 = es2[j];
            int sx = e2.x & SRCMASK;
            int dl = (e2.x >> 25) & 31;
            float eav = __int_as_float(e2.y);
            uint4 ar = nrec[2 * sx];
            xs[t] = nrec[2 * sx + 1];
            uint2 br = ad1L[dl];
            float lg0 = bflo(ar.x) + bflo(br.x) + eav * c56;
            float lg1 = bfhi(ar.x) + bfhi(br.x) + eav * c57;
            float lg2 = bflo(ar.y) + bflo(br.y) + eav * c58;
            float lg3 = bfhi(ar.y) + bfhi(br.y) + eav * c59;
            lg0 = lg0 >= 0.f ? lg0 : 0.2f * lg0;
            lg1 = lg1 >= 0.f ? lg1 : 0.2f * lg1;
            lg2 = lg2 >= 0.f ? lg2 : 0.2f * lg2;
            lg3 = lg3 >= 0.f ? lg3 : 0.2f * lg3;
            wsx[t] = make_uint2(pk2(__expf(lg0), __expf(lg1)),
                                pk2(__expf(lg2), __expf(lg3)));
        }
        __syncthreads();
        int lo = max(go0, C0) - C0, hi = min(go1, C1) - C0;
        for (int jj = lo; jj < hi; ++jj) {
            unsigned xu = ((const unsigned*)&xs[jj])[qh];
            float xv = __uint_as_float((xu << xsl) & 0xFFFF0000u);
            uint2 wv = wsx[jj];
            mh0 = fmaf(bflo(wv.x), xv, mh0);
            mh1 = fmaf(bfhi(wv.x), xv, mh1);
            mh2 = fmaf(bflo(wv.y), xv, mh2);
            mh3 = fmaf(bfhi(wv.y), xv, mh3);
        }
        __syncthreads();
    }
    ms[g][0 * 8 + q] = mh0; ms[g][1 * 8 + q] = mh1;
    ms[g][2 * 8 + q] = mh2; ms[g][3 * 8 + q] = mh3;
    __syncthreads();          // xs/wsx dead from here; hs may now overwrite
    // finish: 8 nodes per wave, lane = channel
    for (int gi = wid * 8; gi < wid * 8 + 8; ++gi) {
        bool has = soffs[gi + 1] > soffs[gi];
        #pragma unroll
        for (int h = 0; h < 4; ++h) {
            float rz = __builtin_amdgcn_rcpf(ms[gi][h * 8 + 7]);
            float a = 0.f;
            #pragma unroll
            for (int k = 0; k < 7; ++k) a = fmaf(ms[gi][h * 8 + k], w1r[k][h], a);
            float mm = (has ? a * rz : 0.f) + b1r[h];
            float hv = mm > 0.f ? mm : (__expf(mm) - 1.f);
            hs[gi][h * 64 + lane] = f2bf(hv);
        }
    }
    __syncthreads();
    // MFMA: 2 node-tiles x 5 col-tiles (ct=4 -> a_src2/a_dst2 columns)
    int row = lane & 15, kg = lane >> 4;
    #pragma unroll
    for (int u = wid; u < 10; u += 4) {
        int nt = u & 1, ct = u >> 1;
        f32x4 acc = {0.f, 0.f, 0.f, 0.f};
        #pragma unroll
        for (int ks = 0; ks < 8; ++ks) {
            bf16x8 av = *(const bf16x8*)&hs[nt * 16 + row][ks * 32 + kg * 8];
            bf16x8 bv = *(const bf16x8*)(W2fr + (((ks * 5 + ct) * 64) + lane) * 8);
            acc = __builtin_amdgcn_mfma_f32_16x16x32_bf16(av, bv, acc, 0, 0, 0);
        }
        if (ct < 4) {
            #pragma unroll
            for (int i = 0; i < 4; ++i)
                xh2f[(n0 + nt * 16 + kg * 4 + i) * 64 + ct * 16 + row] = f2fp8(acc[i]);
        } else if (row == 0) {
            #pragma unroll
            for (int i = 0; i < 4; ++i) a_src2[n0 + nt * 16 + kg * 4 + i] = acc[i];
        } else if (row == 1) {
            #pragma unroll
            for (int i = 0; i < 4; ++i) a_dst2[n0 + nt * 16 + kg * 4 + i] = acc[i];
        }
    }
}

// conv2 normalization + fused cluster pooling; 64-node blocks, 256 threads,
// balanced edge-parallel pass 2 (32 slots x 8 lanes)
__global__ __launch_bounds__(256) void k_zpool(
    const int2* __restrict__ es2, const int* __restrict__ offs,
    const float* __restrict__ a_src2, const float* __restrict__ a_dst2,
    const int* __restrict__ assign, const float* __restrict__ cb,
    const unsigned char* __restrict__ xh2f, const float* __restrict__ x,
    float* __restrict__ partial) {
    __shared__ int soffs[65];
    __shared__ float adL[64];
    __shared__ int asgL[64];
    __shared__ float ewL[1024];
    __shared__ int sL[1024];
    __shared__ float rzL[64];
    __shared__ float zacc[64];
    __shared__ float csum[264];
    int t = threadIdx.x;
    int n0 = blockIdx.x * 64;
    if (t <= 64) soffs[t] = offs[min(n0 + t, NN)];
    if (t < 64) {
        int nn = min(n0 + t, NN - 1);
        adL[t] = a_dst2[nn];
        asgL[t] = assign[nn];
        zacc[t] = 0.f;
    }
    for (int i = t; i < 264; i += 256) csum[i] = 0.f;
    __syncthreads();
    int E0 = soffs[0], E1 = soffs[64];
    int span = E1 - E0;
    float c2 = cb[60];
    #pragma unroll
    for (int c0 = 0; c0 < 1024; c0 += 256) {
        int j = c0 + t;
        if (j < span && j < 1024) {
            int2 e2 = es2[E0 + j];
            int sx = e2.x & SRCMASK;
            int d6 = (e2.x >> 25) & 63;
            float lg = a_src2[sx] + adL[d6] + __int_as_float(e2.y) * c2;
            lg = lg >= 0.f ? lg : 0.2f * lg;
            ewL[j] = __expf(lg);
            sL[j] = e2.x;
        }
    }
    // rare overflow edges: accumulate z via LDS atomics
    for (int j = 1024 + t; j < span; j += 256) {
        int2 e2 = es2[E0 + j];
        int d6 = (e2.x >> 25) & 63;
        float lg = a_src2[e2.x & SRCMASK] + adL[d6] + __int_as_float(e2.y) * c2;
        lg = lg >= 0.f ? lg : 0.2f * lg;
        atomicAdd(&zacc[d6], __expf(lg));
    }
    __syncthreads();
    // per-node z from ewL (4 lanes per node, 64 nodes)
    int gz = t >> 2, q4 = t & 3;
    {
        int lo = soffs[gz] - E0, hi = soffs[gz + 1] - E0;
        int hicap = min(hi, 1024);
        float z = 0.f;
        for (int jj = lo + q4; jj < hicap; jj += 4) z += ewL[jj];
        z += __shfl_xor(z, 1, 64);
        z += __shfl_xor(z, 2, 64);
        if (q4 == 0) rzL[gz] = __builtin_amdgcn_rcpf(z + zacc[gz]);
    }
    __syncthreads();
    // pass 2: edge-parallel slots (32 slots x 8 lanes), 4-cluster predicated regs
    int slot = t >> 3, q = t & 7;
    const unsigned char* pbase = xh2f + q * 8;
    float ac[4][8];
    #pragma unroll
    for (int c = 0; c < 4; ++c)
        #pragma unroll
        for (int k = 0; k < 8; ++k) ac[c][k] = 0.f;
    #pragma unroll 2
    for (int jj = slot; jj < span; jj += 32) {
        int zv; float ew;
        if (jj < 1024) {
            zv = sL[jj];
            ew = ewL[jj];
        } else {
            int2 e2 = es2[E0 + jj];
            zv = e2.x;
            int d6o = (zv >> 25) & 63;
            float lg = a_src2[zv & SRCMASK] + adL[d6o] + __int_as_float(e2.y) * c2;
            lg = lg >= 0.f ? lg : 0.2f * lg;
            ew = __expf(lg);
        }
        int sx = zv & SRCMASK;
        int d6 = (zv >> 25) & 63;
        float wv = ew * rzL[d6];
        int cc = asgL[d6];
        uint2 u = *(const uint2*)(pbase + sx * 64);
        float v0 = dfp8(u.x & 255u), v1 = dfp8((u.x >> 8) & 255u);
        float v2 = dfp8((u.x >> 16) & 255u), v3 = dfp8(u.x >> 24);
        float v4 = dfp8(u.y & 255u), v5 = dfp8((u.y >> 8) & 255u);
        float v6 = dfp8((u.y >> 16) & 255u), v7 = dfp8(u.y >> 24);
        #pragma unroll
        for (int c = 0; c < 4; ++c) {
            float wc = (cc == c) ? wv : 0.f;
            ac[c][0] = fmaf(wc, v0, ac[c][0]);
            ac[c][1] = fmaf(wc, v1, ac[c][1]);
            ac[c][2] = fmaf(wc, v2, ac[c][2]);
            ac[c][3] = fmaf(wc, v3, ac[c][3]);
            ac[c][4] = fmaf(wc, v4, ac[c][4]);
            ac[c][5] = fmaf(wc, v5, ac[c][5]);
            ac[c][6] = fmaf(wc, v6, ac[c][6]);
            ac[c][7] = fmaf(wc, v7, ac[c][7]);
        }
    }
    // fold 8 slots per wave (lane bits 3,4,5), then 8 lanes/wave do LDS atomics
    #pragma unroll
    for (int c = 0; c < 4; ++c)
        #pragma unroll
        for (int k = 0; k < 8; ++k) {
            float v = ac[c][k];
            v += __shfl_xor(v, 8, 64);
            v += __shfl_xor(v, 16, 64);
            v += __shfl_xor(v, 32, 64);
            ac[c][k] = v;
        }
    if (((t >> 3) & 7) == 0) {
        #pragma unroll
        for (int c = 0; c < 4; ++c)
            #pragma unroll
            for (int k = 0; k < 8; ++k)
                atomicAdd(&csum[c * 64 + q * 8 + k], ac[c][k]);
    }
    if (t < 64 && n0 + t < NN) {
        int c = asgL[t];
        atomicAdd(&csum[256 + c], 1.f);
        atomicAdd(&csum[260 + c], x[(n0 + t) * 7 + 6]);
    }
    __syncthreads();
    for (int i = t; i < 264; i += 256) partial[blockIdx.x * 264 + i] = csum[i];
}

// stage A: coalesced chunk reduce of partial[NZB2][264] -> part2[NRA][264]
__global__ __launch_bounds__(256) void k_redA(const float* __restrict__ partial,
                                              float* __restrict__ part2) {
    int gblk = blockIdx.x;
    int b0 = gblk * 64, b1 = min(b0 + 64, NZB2);
    int t = threadIdx.x;
    for (int i = t; i < 264; i += 256) {
        float s = 0.f;
        for (int b = b0; b < b1; ++b) s += partial[b * 264 + i];
        part2[gblk * 264 + i] = s;
    }
}

// final head (256 threads): fold part2 -> cluster means (+cnt*b2), actor + critic
__global__ __launch_bounds__(256) void k_head(
    const float* __restrict__ part2, const float* __restrict__ b2,
    const float* __restrict__ A1, const float* __restrict__ ba1,
    const float* __restrict__ A2, const float* __restrict__ ba2,
    const float* __restrict__ C1, const float* __restrict__ bc1,
    const float* __restrict__ C2, const float* __restrict__ bc2,
    float* __restrict__ out) {
    __shared__ float gaccL[264];
    __shared__ float zc[4][64];
    __shared__ float cfs[4];
    __shared__ float logits[4];
    __shared__ float vpart[4][64];
    int t = threadIdx.x;
    for (int i = t; i < 264; i += 256) {
        float s = 0.f;
        for (int g = 0; g < NRA; ++g) s += part2[g * 264 + i];
        gaccL[i] = s;
    }
    __syncthreads();
    int j = t & 63, wv = t >> 6;   // wave wv handles cluster wv
    float cnt = gaccL[256 + wv];
    float den = fmaxf(cnt, 1.f);
    zc[wv][j] = (cnt > 0.f) ? (gaccL[wv * 64 + j] + cnt * b2[j]) / den : 0.f;
    if (t < 4) {
        float cc = gaccL[256 + t];
        cfs[t] = (cc > 0.f) ? gaccL[260 + t] / fmaxf(cc, 1.f) : 0.f;
    }
    __syncthreads();
    // actor: cluster wv
    float tv = ba1[j];
    for (int k = 0; k < 64; ++k) tv = fmaf(zc[wv][k], A1[k * 64 + j], tv);
    tv = fmaf(cfs[wv], A1[64 * 64 + j], tv);
    tv = fmaxf(tv, 0.f);
    float sred = wave_reduce_sum(tv * A2[j]);
    if (j == 0) logits[wv] = sred + ba2[0];
    // critic partials: wave wv covers k in [wv*64, (wv+1)*64)
    float vj = (wv == 0) ? bc1[j] : 0.f;
    for (int kk = 0; kk < 64; ++kk) vj = fmaf(zc[wv][kk], C1[(wv * 64 + kk) * 64 + j], vj);
    vpart[wv][j] = vj;
    __syncthreads();
    if (wv == 0) {
        float vv = fmaxf(vpart[0][j] + vpart[1][j] + vpart[2][j] + vpart[3][j], 0.f);
        float v = wave_reduce_sum(vv * C2[j]);
        if (j == 0) {
            float m = fmaxf(fmaxf(logits[0], logits[1]), fmaxf(logits[2], logits[3]));
            float e0 = __expf(logits[0] - m), e1 = __expf(logits[1] - m);
            float e2 = __expf(logits[2] - m), e3 = __expf(logits[3] - m);
            float sum = e0 + e1 + e2 + e3;
            out[0] = e0 / sum; out[1] = e1 / sum; out[2] = e2 / sum; out[3] = e3 / sum;
            out[4] = v + bc2[0];
        }
    }
    out[5 + wv * 64 + j] = zc[wv][j];
}

extern "C" void kernel_launch(void* const* d_in, const int* in_sizes, int n_in,
                              void* d_out, int out_size, void* d_ws, size_t ws_size,
                              hipStream_t stream) {
    const float* x    = (const float*)d_in[0];
    const int*   ei   = (const int*)d_in[1];
    const float* ea   = (const float*)d_in[2];
    const int*   asg  = (const int*)d_in[3];
    const float* W1   = (const float*)d_in[4];
    const float* as1  = (const float*)d_in[5];
    const float* ad1  = (const float*)d_in[6];
    const float* We1  = (const float*)d_in[7];
    const float* ae1  = (const float*)d_in[8];
    const float* b1   = (const float*)d_in[9];
    const float* W2   = (const float*)d_in[10];
    const float* as2  = (const float*)d_in[11];
    const float* ad2  = (const float*)d_in[12];
    const float* We2  = (const float*)d_in[13];
    const float* ae2  = (const float*)d_in[14];
    const float* b2   = (const float*)d_in[15];
    const float* A1   = (const float*)d_in[16];
    const float* ba1  = (const float*)d_in[17];
    const float* A2   = (const float*)d_in[18];
    const float* ba2  = (const float*)d_in[19];
    const float* C1   = (const float*)d_in[20];
    const float* bc1  = (const float*)d_in[21];
    const float* C2   = (const float*)d_in[22];
    const float* bc2  = (const float*)d_in[23];
    const int* src = ei;
    const int* dst = ei + NE;

    char* w = (char*)d_ws;
    size_t off = 0;
    auto alloc = [&](size_t bytes) -> void* {
        void* p = w + off;
        off += (bytes + 255) & ~(size_t)255;
        return p;
    };
    int*   hist   = (int*)alloc(NN * sizeof(int));
    float* partial= (float*)alloc((size_t)NZB2 * 264 * sizeof(float));
    float* part2  = (float*)alloc((size_t)NRA * 264 * sizeof(float));
    uint4* nrec   = (uint4*)alloc((size_t)NN * 2 * sizeof(uint4));
    float* a_src2 = (float*)alloc(NN * sizeof(float));
    float* a_dst2 = (float*)alloc(NN * sizeof(float));
    int*   offs   = (int*)alloc((NN + 1) * sizeof(int));
    int*   rank   = (int*)alloc(NE * sizeof(int));
    int*   bsum   = (int*)alloc(128 * sizeof(int));
    int*   bexcl  = (int*)alloc(128 * sizeof(int));
    int2*  es2    = (int2*)alloc(NE * sizeof(int2));
    unsigned char* xh2f = (unsigned char*)alloc((size_t)NN * 64 * sizeof(unsigned char));
    unsigned short* W2fr = (unsigned short*)alloc(20480 * sizeof(unsigned short));
    float* cb     = (float*)alloc(64 * sizeof(float));
    (void)ws_size; (void)n_in; (void)in_sizes; (void)out_size;

    k_zero<<<98, 256, 0, stream>>>((int4*)hist);
    k_pre<<<81, 256, 0, stream>>>(W1, as1, ad1, We1, ae1, We2, ae2, W2, as2, ad2, cb, W2fr);
    k_node1h<<<(NN + 255) / 256, 256, 0, stream>>>(x, cb, dst, nrec, hist, rank);
    k_scanA<<<98, 1024, 0, stream>>>(hist, bsum);
    k_scanB<<<1, 128, 0, stream>>>(bsum, bexcl);
    k_scanC<<<98, 1024, 0, stream>>>(hist, bexcl, offs);
    k_scatter<<<(NE / 2 + 255) / 256, 256, 0, stream>>>(src, dst, ea, rank, offs, es2);
    k_conv1red<<<NN / 32, 256, 0, stream>>>(nrec, W1, b1, cb, offs, es2,
                                            W2fr, xh2f, a_src2, a_dst2);
    k_zpool<<<NZB2, 256, 0, stream>>>(es2, offs, a_src2, a_dst2, asg, cb, xh2f, x, partial);
    k_redA<<<NRA, 256, 0, stream>>>(partial, part2);
    k_head<<<1, 256, 0, stream>>>(part2, b2, A1, ba1, A2, ba2, C1, bc1, C2, bc2, (float*)d_out);
}